// Round 1
// 93.218 us; speedup vs baseline: 1.0575x; 1.0575x over previous
//
#include <hip/hip_runtime.h>
#include <math.h>

// Problem constants (fixed shapes from reference)
#define KNUM 256
#define HH 62
#define WW 64
#define BB 768            // N*C = 4*192
#define JV 1024           // vectors per plane = W*Hp/D = 64*64/4
#define M_TOT (BB*JV)     // 786432
#define QL_SIZE (BB*HH*WW) // 3047424

// d_out layout (concatenated tuple, float32):
#define OFF_MSE   QL_SIZE
#define OFF_INDS  (QL_SIZE + 1)
#define OFF_RATE  (OFF_INDS + M_TOT)

// d_ws layout (floats): per-block partials
#define WS_MSE  0
#define WS_RATE 768

#define XT_STRIDE 65   // bank(w*65+h) = (w+h)%32 -> all phases <=2-way (conflict-free)

typedef float v2f __attribute__((ext_vector_type(2)));
typedef float v4f __attribute__((ext_vector_type(4)));

// v_pk_fma_f32 d = c*y + acc, with src1 (y) broadcast from ONE 32-bit half to
// both output halves via op_sel/op_sel_hi -> y needs no splat registers.
// lo-broadcast: lo half reads y.lo (op_sel[1]=0), hi half reads y.lo (op_sel_hi[1]=0)
// hi-broadcast: lo half reads y.hi (op_sel[1]=1), hi half reads y.hi (op_sel_hi[1]=1)
__device__ __forceinline__ v2f pk_fma_ylo(v2f c, v2f y, v2f acc) {
    v2f d;
    asm("v_pk_fma_f32 %0, %1, %2, %3 op_sel:[0,0,0] op_sel_hi:[1,0,1]"
        : "=v"(d) : "v"(c), "v"(y), "v"(acc));
    return d;
}
__device__ __forceinline__ v2f pk_fma_ylo_acc(v2f c, v2f y, v2f d) {
    asm("v_pk_fma_f32 %0, %1, %2, %0 op_sel:[0,0,0] op_sel_hi:[1,0,1]"
        : "+v"(d) : "v"(c), "v"(y));
    return d;
}
__device__ __forceinline__ v2f pk_fma_yhi_acc(v2f c, v2f y, v2f d) {
    asm("v_pk_fma_f32 %0, %1, %2, %0 op_sel:[0,1,0] op_sel_hi:[1,1,1]"
        : "+v"(d) : "v"(c), "v"(y));
    return d;
}

// 768 blocks x 256 threads, 4 vectors/thread: 3 blocks/CU, 3 waves/SIMD for
// latency hiding; (256,4) caps VGPR at 128 (keeps 3 blocks resident) without
// strangling the allocator (R4: heuristic gave 68 -> remat movs everywhere).
__launch_bounds__(256, 4)
__global__ void vq_main(const float* __restrict__ latents,
                        const float* __restrict__ codebook,
                        const float* __restrict__ log_pmf,
                        float* __restrict__ ws_out,
                        float* __restrict__ out) {
    __shared__ __align__(16) float xt[64 * XT_STRIDE];  // transposed plane [w][h]
    __shared__ __align__(16) float tab[128 * 10];       // pair-interleaved codebook
    __shared__ float4 cbv[KNUM];                        // epilogue gather
    __shared__ float  l2v[KNUM];
    __shared__ float  wred[8];

    const int t = threadIdx.x;
    const int b = blockIdx.x;
    const float* lat = latents + (size_t)b * (HH * WW);

    // ---- stage pair-interleaved codebook table (first 128 threads) ----
    // Layout per pair p (codewords 2p, 2p+1), 10 floats at tab[p*10]:
    //   {cx0,cx1, cy0,cy1, cz0,cz1, cw0,cw1, q0,q1}
    // A group g = pairs {2g, 2g+1} = 80 bytes, 16B-aligned -> 5x ds_read_b128.
    if (t < 128) {
        float4 c0 = ((const float4*)codebook)[2 * t];
        float4 c1 = ((const float4*)codebook)[2 * t + 1];
        float l20 = log_pmf[2 * t]     * (-1.44269504088896340736f);
        float l21 = log_pmf[2 * t + 1] * (-1.44269504088896340736f);
        float q0 = c0.x * c0.x + c0.y * c0.y + c0.z * c0.z + c0.w * c0.w + l20 * 100.0f;
        float q1 = c1.x * c1.x + c1.y * c1.y + c1.z * c1.z + c1.w * c1.w + l21 * 100.0f;
        float* e = &tab[t * 10];
        e[0] = c0.x; e[1] = c1.x;
        e[2] = c0.y; e[3] = c1.y;
        e[4] = c0.z; e[5] = c1.z;
        e[6] = c0.w; e[7] = c1.w;
        e[8] = q0;   e[9] = q1;
        cbv[2 * t] = c0; cbv[2 * t + 1] = c1;
        l2v[2 * t] = l20; l2v[2 * t + 1] = l21;
    }

    // ---- stage latents plane transposed into LDS (pad rows 62,63 = rows 60,61) ----
    for (int idx = t; idx < (HH * WW / 4); idx += 256) {
        int h  = idx >> 4;     // row 0..61
        int wq = idx & 15;     // float4 column
        float4 v = ((const float4*)lat)[idx];
        int w0 = wq * 4;
        xt[(w0 + 0) * XT_STRIDE + h] = v.x;
        xt[(w0 + 1) * XT_STRIDE + h] = v.y;
        xt[(w0 + 2) * XT_STRIDE + h] = v.z;
        xt[(w0 + 3) * XT_STRIDE + h] = v.w;
        if (h >= 60) {     // replicate rows 60,61 -> 62,63
            int h2 = h + 2;
            xt[(w0 + 0) * XT_STRIDE + h2] = v.x;
            xt[(w0 + 1) * XT_STRIDE + h2] = v.y;
            xt[(w0 + 2) * XT_STRIDE + h2] = v.z;
            xt[(w0 + 3) * XT_STRIDE + h2] = v.w;
        }
    }
    __syncthreads();

    // ---- per-thread: 4 vectors j = t + 256*i; y = -2x as natural pairs ----
    v2f y01[4], y23[4];    // {yx,yy}, {yz,yw} -- 4 VGPRs per vector
    float dmin[4];
    int   gmin[4];         // winning GROUP of 4 codewords (index recovered after loop)
#pragma unroll
    for (int i = 0; i < 4; ++i) {
        int j  = t + 256 * i;
        int w  = j >> 4;
        int hc = j & 15;
        const float* p = &xt[w * XT_STRIDE + hc * 4];
        y01[i] = (v2f){-2.0f * p[0], -2.0f * p[1]};
        y23[i] = (v2f){-2.0f * p[2], -2.0f * p[3]};
        dmin[i] = INFINITY;
        gmin[i] = 0;
    }

    // ---- running min over 64 groups of 4 codewords ----
    // Per group per vector: 8 pk_fma + 2 v_min3 + 1 cmp + 1 cndmask = 12 VALU
    // (vs 18 for per-pair index tracking). Winning group recovered exactly below
    // by bit-identical recompute; strict < keeps the earliest group on ties,
    // preserving jnp.argmin first-occurrence semantics.
    // tab reads: 5x ds_read_b128 per group, wave-uniform broadcast (conflict-free).
#pragma unroll 2
    for (int g = 0; g < 64; ++g) {
        const v4f* tg = (const v4f*)&tab[g * 20];
        v4f F0 = tg[0], F1 = tg[1], F2 = tg[2], F3 = tg[3], F4 = tg[4];
        v2f cxa = __builtin_shufflevector(F0, F0, 0, 1);
        v2f cya = __builtin_shufflevector(F0, F0, 2, 3);
        v2f cza = __builtin_shufflevector(F1, F1, 0, 1);
        v2f cwa = __builtin_shufflevector(F1, F1, 2, 3);
        v2f qqa = __builtin_shufflevector(F2, F2, 0, 1);
        v2f cxb = __builtin_shufflevector(F2, F2, 2, 3);
        v2f cyb = __builtin_shufflevector(F3, F3, 0, 1);
        v2f czb = __builtin_shufflevector(F3, F3, 2, 3);
        v2f cwb = __builtin_shufflevector(F4, F4, 0, 1);
        v2f qqb = __builtin_shufflevector(F4, F4, 2, 3);
#pragma unroll
        for (int i = 0; i < 4; ++i) {
            v2f da = pk_fma_ylo(cxa, y01[i], qqa);       // + yx*{cx0,cx1}
            da = pk_fma_yhi_acc(cya, y01[i], da);        // + yy*{cy0,cy1}
            da = pk_fma_ylo_acc(cza, y23[i], da);        // + yz*{cz0,cz1}
            da = pk_fma_yhi_acc(cwa, y23[i], da);        // + yw*{cw0,cw1}
            v2f db = pk_fma_ylo(cxb, y01[i], qqb);
            db = pk_fma_yhi_acc(cyb, y01[i], db);
            db = pk_fma_ylo_acc(czb, y23[i], db);
            db = pk_fma_yhi_acc(cwb, y23[i], db);
            float nm = fminf(fminf(db.x, db.y), dmin[i]);   // v_min3_f32
            nm = fminf(fminf(da.x, da.y), nm);              // v_min3_f32
            gmin[i] = (nm < dmin[i]) ? g : gmin[i];         // cmp + cndmask
            dmin[i] = nm;
        }
    }

    // ---- exact index recovery: recompute the winning group's 4 distances with
    //      the bit-identical pk_fma sequence; first match (in k order) wins ----
    int kmin[4];
#pragma unroll
    for (int i = 0; i < 4; ++i) {
        int g = gmin[i];
        const v4f* tg = (const v4f*)&tab[g * 20];
        v4f F0 = tg[0], F1 = tg[1], F2 = tg[2], F3 = tg[3], F4 = tg[4];
        v2f cxa = __builtin_shufflevector(F0, F0, 0, 1);
        v2f cya = __builtin_shufflevector(F0, F0, 2, 3);
        v2f cza = __builtin_shufflevector(F1, F1, 0, 1);
        v2f cwa = __builtin_shufflevector(F1, F1, 2, 3);
        v2f qqa = __builtin_shufflevector(F2, F2, 0, 1);
        v2f cxb = __builtin_shufflevector(F2, F2, 2, 3);
        v2f cyb = __builtin_shufflevector(F3, F3, 0, 1);
        v2f czb = __builtin_shufflevector(F3, F3, 2, 3);
        v2f cwb = __builtin_shufflevector(F4, F4, 0, 1);
        v2f qqb = __builtin_shufflevector(F4, F4, 2, 3);
        v2f da = pk_fma_ylo(cxa, y01[i], qqa);
        da = pk_fma_yhi_acc(cya, y01[i], da);
        da = pk_fma_ylo_acc(cza, y23[i], da);
        da = pk_fma_yhi_acc(cwa, y23[i], da);
        v2f db = pk_fma_ylo(cxb, y01[i], qqb);
        db = pk_fma_yhi_acc(cyb, y01[i], db);
        db = pk_fma_ylo_acc(czb, y23[i], db);
        db = pk_fma_yhi_acc(cwb, y23[i], db);
        int k = g * 4;
        int idx = k + 3;
        idx = (db.x == dmin[i]) ? k + 2 : idx;   // reverse-order overrides:
        idx = (da.y == dmin[i]) ? k + 1 : idx;   // earliest match ends up in idx
        idx = (da.x == dmin[i]) ? k     : idx;
        kmin[i] = idx;
    }

    // ---- epilogue per vector: gather q, accumulate mse/rate, write q in place, write ind ----
    float mse_acc = 0.0f;
    float rate_acc = 0.0f;
#pragma unroll
    for (int i = 0; i < 4; ++i) {
        int j  = t + 256 * i;
        int w  = j >> 4;
        int hc = j & 15;
        float4 c = cbv[kmin[i]];
        rate_acc += l2v[kmin[i]];
        float e0 = fmaf(0.5f, y01[i].x, c.x);   // c - x
        float e1 = fmaf(0.5f, y01[i].y, c.y);
        float e2 = fmaf(0.5f, y23[i].x, c.z);
        float e3 = fmaf(0.5f, y23[i].y, c.w);
        mse_acc += e0 * e0 + e1 * e1 + e2 * e2 + e3 * e3;
        float* p = &xt[w * XT_STRIDE + hc * 4];
        p[0] = c.x; p[1] = c.y; p[2] = c.z; p[3] = c.w;   // overwrite x with q
        out[OFF_INDS + (size_t)b * JV + j] = (float)kmin[i];
    }
    __syncthreads();

    // ---- coalesced crop/transpose write-out: ql[b, h, w] = xt[w][h], h < 62 ----
    for (int idx = t; idx < HH * WW; idx += 256) {
        int h = idx >> 6;
        int w = idx & 63;
        out[(size_t)b * (HH * WW) + idx] = xt[w * XT_STRIDE + h];
    }

    // ---- block reduction of mse/rate -> per-block partial (plain store) ----
#pragma unroll
    for (int off = 32; off > 0; off >>= 1) {
        mse_acc  += __shfl_down(mse_acc, off, 64);
        rate_acc += __shfl_down(rate_acc, off, 64);
    }
    int wave = t >> 6, lane = t & 63;
    if (lane == 0) { wred[wave] = mse_acc; wred[4 + wave] = rate_acc; }
    __syncthreads();
    if (t == 0) {
        ws_out[WS_MSE + b]  = wred[0] + wred[1] + wred[2] + wred[3];
        ws_out[WS_RATE + b] = wred[4] + wred[5] + wred[6] + wred[7];
    }
}

__global__ void vq_reduce(const float* __restrict__ ws, float* __restrict__ out) {
    __shared__ float wred[8];
    int t = threadIdx.x;   // 256 threads
    float m = ws[WS_MSE + t]  + ws[WS_MSE + 256 + t]  + ws[WS_MSE + 512 + t];
    float r = ws[WS_RATE + t] + ws[WS_RATE + 256 + t] + ws[WS_RATE + 512 + t];
#pragma unroll
    for (int off = 32; off > 0; off >>= 1) {
        m += __shfl_down(m, off, 64);
        r += __shfl_down(r, off, 64);
    }
    int wave = t >> 6, lane = t & 63;
    if (lane == 0) { wred[wave] = m; wred[4 + wave] = r; }
    __syncthreads();
    if (t == 0) {
        out[OFF_MSE]      = (wred[0] + wred[1] + wred[2] + wred[3]) * (1.0f / 3145728.0f);
        out[OFF_RATE]     = wred[4] + wred[5] + wred[6] + wred[7];
        out[OFF_RATE + 1] = 0.0f;
        out[OFF_RATE + 2] = 0.0f;
    }
}

extern "C" void kernel_launch(void* const* d_in, const int* in_sizes, int n_in,
                              void* d_out, int out_size, void* d_ws, size_t ws_size,
                              hipStream_t stream) {
    const float* latents  = (const float*)d_in[0];
    const float* codebook = (const float*)d_in[1];
    const float* log_pmf  = (const float*)d_in[2];
    float* out = (float*)d_out;
    float* ws  = (float*)d_ws;

    vq_main<<<BB, 256, 0, stream>>>(latents, codebook, log_pmf, ws, out);
    vq_reduce<<<1, 256, 0, stream>>>(ws, out);
}

// Round 2
// 93.079 us; speedup vs baseline: 1.0591x; 1.0015x over previous
//
#include <hip/hip_runtime.h>
#include <math.h>

// Problem constants (fixed shapes from reference)
#define KNUM 256
#define HH 62
#define WW 64
#define BB 768            // N*C = 4*192
#define JV 1024           // vectors per plane = W*Hp/D = 64*64/4
#define M_TOT (BB*JV)     // 786432
#define QL_SIZE (BB*HH*WW) // 3047424

// d_out layout (concatenated tuple, float32):
#define OFF_MSE   QL_SIZE
#define OFF_INDS  (QL_SIZE + 1)
#define OFF_RATE  (OFF_INDS + M_TOT)

// d_ws layout (floats): per-block partials
#define WS_MSE  0
#define WS_RATE 768

#define XT_STRIDE 65   // bank(w*65+h) = (w+h)%32 -> all phases <=2-way (conflict-free)

typedef float v2f __attribute__((ext_vector_type(2)));
typedef float v4f __attribute__((ext_vector_type(4)));

// v_pk_fma_f32 d = c*y + acc, with src1 (y) broadcast from ONE 32-bit half to
// both output halves via op_sel/op_sel_hi -> y needs no splat registers.
// lo-broadcast: lo half reads y.lo (op_sel[1]=0), hi half reads y.lo (op_sel_hi[1]=0)
// hi-broadcast: lo half reads y.hi (op_sel[1]=1), hi half reads y.hi (op_sel_hi[1]=1)
__device__ __forceinline__ v2f pk_fma_ylo(v2f c, v2f y, v2f acc) {
    v2f d;
    asm("v_pk_fma_f32 %0, %1, %2, %3 op_sel:[0,0,0] op_sel_hi:[1,0,1]"
        : "=v"(d) : "v"(c), "v"(y), "v"(acc));
    return d;
}
__device__ __forceinline__ v2f pk_fma_ylo_acc(v2f c, v2f y, v2f d) {
    asm("v_pk_fma_f32 %0, %1, %2, %0 op_sel:[0,0,0] op_sel_hi:[1,0,1]"
        : "+v"(d) : "v"(c), "v"(y));
    return d;
}
__device__ __forceinline__ v2f pk_fma_yhi_acc(v2f c, v2f y, v2f d) {
    asm("v_pk_fma_f32 %0, %1, %2, %0 op_sel:[0,1,0] op_sel_hi:[1,1,1]"
        : "+v"(d) : "v"(c), "v"(y));
    return d;
}

// Compute the 4 distance-pairs of one group of 8 codewords (pairs p..p+3 of the
// interleaved table at tg = &tab[g8*40], read as 10x v4f). Bit-identical
// sequence is reused for the post-loop index recovery.
#define GROUP8_DISTS(tg, y01i, y23i, da, db, dc, dd)                         \
    do {                                                                     \
        v4f G0 = (tg)[0], G1 = (tg)[1], G2 = (tg)[2], G3 = (tg)[3], G4 = (tg)[4]; \
        v4f G5 = (tg)[5], G6 = (tg)[6], G7 = (tg)[7], G8 = (tg)[8], G9 = (tg)[9]; \
        v2f cxa = __builtin_shufflevector(G0, G0, 0, 1);                     \
        v2f cya = __builtin_shufflevector(G0, G0, 2, 3);                     \
        v2f cza = __builtin_shufflevector(G1, G1, 0, 1);                     \
        v2f cwa = __builtin_shufflevector(G1, G1, 2, 3);                     \
        v2f qqa = __builtin_shufflevector(G2, G2, 0, 1);                     \
        v2f cxb = __builtin_shufflevector(G2, G2, 2, 3);                     \
        v2f cyb = __builtin_shufflevector(G3, G3, 0, 1);                     \
        v2f czb = __builtin_shufflevector(G3, G3, 2, 3);                     \
        v2f cwb = __builtin_shufflevector(G4, G4, 0, 1);                     \
        v2f qqb = __builtin_shufflevector(G4, G4, 2, 3);                     \
        v2f cxc = __builtin_shufflevector(G5, G5, 0, 1);                     \
        v2f cyc = __builtin_shufflevector(G5, G5, 2, 3);                     \
        v2f czc = __builtin_shufflevector(G6, G6, 0, 1);                     \
        v2f cwc = __builtin_shufflevector(G6, G6, 2, 3);                     \
        v2f qqc = __builtin_shufflevector(G7, G7, 0, 1);                     \
        v2f cxd = __builtin_shufflevector(G7, G7, 2, 3);                     \
        v2f cyd = __builtin_shufflevector(G8, G8, 0, 1);                     \
        v2f czd = __builtin_shufflevector(G8, G8, 2, 3);                     \
        v2f cwd = __builtin_shufflevector(G9, G9, 0, 1);                     \
        v2f qqd = __builtin_shufflevector(G9, G9, 2, 3);                     \
        da = pk_fma_ylo(cxa, y01i, qqa);                                     \
        da = pk_fma_yhi_acc(cya, y01i, da);                                  \
        da = pk_fma_ylo_acc(cza, y23i, da);                                  \
        da = pk_fma_yhi_acc(cwa, y23i, da);                                  \
        db = pk_fma_ylo(cxb, y01i, qqb);                                     \
        db = pk_fma_yhi_acc(cyb, y01i, db);                                  \
        db = pk_fma_ylo_acc(czb, y23i, db);                                  \
        db = pk_fma_yhi_acc(cwb, y23i, db);                                  \
        dc = pk_fma_ylo(cxc, y01i, qqc);                                     \
        dc = pk_fma_yhi_acc(cyc, y01i, dc);                                  \
        dc = pk_fma_ylo_acc(czc, y23i, dc);                                  \
        dc = pk_fma_yhi_acc(cwc, y23i, dc);                                  \
        dd = pk_fma_ylo(cxd, y01i, qqd);                                     \
        dd = pk_fma_yhi_acc(cyd, y01i, dd);                                  \
        dd = pk_fma_ylo_acc(czd, y23i, dd);                                  \
        dd = pk_fma_yhi_acc(cwd, y23i, dd);                                  \
    } while (0)

// 768 blocks x 256 threads, 4 vectors/thread: 3 blocks/CU, 3 waves/SIMD for
// latency hiding; (256,4) caps VGPR at 128 (keeps 3 blocks resident) without
// strangling the allocator (R4: heuristic gave 68 -> remat movs everywhere).
__launch_bounds__(256, 4)
__global__ void vq_main(const float* __restrict__ latents,
                        const float* __restrict__ codebook,
                        const float* __restrict__ log_pmf,
                        float* __restrict__ ws_out,
                        float* __restrict__ out) {
    __shared__ __align__(16) float xt[64 * XT_STRIDE];  // transposed plane [w][h]
    __shared__ __align__(16) float tab[128 * 10];       // pair-interleaved codebook
    __shared__ float4 cbv[KNUM];                        // epilogue gather
    __shared__ float  l2v[KNUM];
    __shared__ float  wred[8];

    const int t = threadIdx.x;
    const int b = blockIdx.x;
    const float* lat = latents + (size_t)b * (HH * WW);

    // ---- stage pair-interleaved codebook table (first 128 threads) ----
    // Layout per pair p (codewords 2p, 2p+1), 10 floats at tab[p*10]:
    //   {cx0,cx1, cy0,cy1, cz0,cz1, cw0,cw1, q0,q1}
    // A group of 8 codewords = 4 pairs = 160 B, 16B-aligned -> 10x ds_read_b128.
    if (t < 128) {
        float4 c0 = ((const float4*)codebook)[2 * t];
        float4 c1 = ((const float4*)codebook)[2 * t + 1];
        float l20 = log_pmf[2 * t]     * (-1.44269504088896340736f);
        float l21 = log_pmf[2 * t + 1] * (-1.44269504088896340736f);
        float q0 = c0.x * c0.x + c0.y * c0.y + c0.z * c0.z + c0.w * c0.w + l20 * 100.0f;
        float q1 = c1.x * c1.x + c1.y * c1.y + c1.z * c1.z + c1.w * c1.w + l21 * 100.0f;
        float* e = &tab[t * 10];
        e[0] = c0.x; e[1] = c1.x;
        e[2] = c0.y; e[3] = c1.y;
        e[4] = c0.z; e[5] = c1.z;
        e[6] = c0.w; e[7] = c1.w;
        e[8] = q0;   e[9] = q1;
        cbv[2 * t] = c0; cbv[2 * t + 1] = c1;
        l2v[2 * t] = l20; l2v[2 * t + 1] = l21;
    }

    // ---- stage latents plane transposed into LDS (pad rows 62,63 = rows 60,61) ----
    for (int idx = t; idx < (HH * WW / 4); idx += 256) {
        int h  = idx >> 4;     // row 0..61
        int wq = idx & 15;     // float4 column
        float4 v = ((const float4*)lat)[idx];
        int w0 = wq * 4;
        xt[(w0 + 0) * XT_STRIDE + h] = v.x;
        xt[(w0 + 1) * XT_STRIDE + h] = v.y;
        xt[(w0 + 2) * XT_STRIDE + h] = v.z;
        xt[(w0 + 3) * XT_STRIDE + h] = v.w;
        if (h >= 60) {     // replicate rows 60,61 -> 62,63
            int h2 = h + 2;
            xt[(w0 + 0) * XT_STRIDE + h2] = v.x;
            xt[(w0 + 1) * XT_STRIDE + h2] = v.y;
            xt[(w0 + 2) * XT_STRIDE + h2] = v.z;
            xt[(w0 + 3) * XT_STRIDE + h2] = v.w;
        }
    }
    __syncthreads();

    // ---- per-thread: 4 vectors j = t + 256*i; y = -2x as natural pairs ----
    v2f y01[4], y23[4];    // {yx,yy}, {yz,yw} -- 4 VGPRs per vector
    float dmin[4];
    int   gmin[4];         // winning GROUP of 8 codewords (index recovered after loop)
#pragma unroll
    for (int i = 0; i < 4; ++i) {
        int j  = t + 256 * i;
        int w  = j >> 4;
        int hc = j & 15;
        const float* p = &xt[w * XT_STRIDE + hc * 4];
        y01[i] = (v2f){-2.0f * p[0], -2.0f * p[1]};
        y23[i] = (v2f){-2.0f * p[2], -2.0f * p[3]};
        dmin[i] = INFINITY;
        gmin[i] = 0;
    }

    // ---- running min over 32 groups of 8 codewords ----
    // Per group per vector: 16 pk_fma + 4 v_min3 + 1 cmp + 1 cndmask = 22 VALU
    // = 2.75 VALU/codeword (2.0 is the packed-FMA floor). Winning group recovered
    // exactly below by bit-identical recompute; strict < keeps the earliest group
    // on ties, preserving jnp.argmin first-occurrence semantics.
    // tab reads: 10x ds_read_b128 per group, wave-uniform broadcast (conflict-free).
#pragma unroll 1
    for (int g8 = 0; g8 < 32; ++g8) {
        const v4f* tg = (const v4f*)&tab[g8 * 40];
#pragma unroll
        for (int i = 0; i < 4; ++i) {
            v2f da, db, dc, dd;
            GROUP8_DISTS(tg, y01[i], y23[i], da, db, dc, dd);
            float nm1 = fminf(fminf(da.x, da.y), db.x);     // v_min3_f32
            float nm2 = fminf(fminf(db.y, dc.x), dc.y);     // v_min3_f32
            float nm3 = fminf(fminf(dd.x, dd.y), dmin[i]);  // v_min3_f32
            float nm  = fminf(fminf(nm1, nm2), nm3);        // v_min3_f32
            gmin[i] = (nm < dmin[i]) ? g8 : gmin[i];        // cmp + cndmask
            dmin[i] = nm;
        }
    }

    // ---- exact index recovery: recompute the winning group's 8 distances with
    //      the bit-identical pk_fma sequence; first match (in k order) wins ----
    int kmin[4];
#pragma unroll
    for (int i = 0; i < 4; ++i) {
        const v4f* tg = (const v4f*)&tab[gmin[i] * 40];
        v2f da, db, dc, dd;
        GROUP8_DISTS(tg, y01[i], y23[i], da, db, dc, dd);
        int k = gmin[i] * 8;
        int idx = k + 7;
        idx = (dd.x == dmin[i]) ? k + 6 : idx;   // reverse-order overrides:
        idx = (dc.y == dmin[i]) ? k + 5 : idx;   // earliest match ends up in idx
        idx = (dc.x == dmin[i]) ? k + 4 : idx;
        idx = (db.y == dmin[i]) ? k + 3 : idx;
        idx = (db.x == dmin[i]) ? k + 2 : idx;
        idx = (da.y == dmin[i]) ? k + 1 : idx;
        idx = (da.x == dmin[i]) ? k     : idx;
        kmin[i] = idx;
    }

    // ---- epilogue per vector: gather q, accumulate mse/rate, write q in place, write ind ----
    float mse_acc = 0.0f;
    float rate_acc = 0.0f;
#pragma unroll
    for (int i = 0; i < 4; ++i) {
        int j  = t + 256 * i;
        int w  = j >> 4;
        int hc = j & 15;
        float4 c = cbv[kmin[i]];
        rate_acc += l2v[kmin[i]];
        float e0 = fmaf(0.5f, y01[i].x, c.x);   // c - x
        float e1 = fmaf(0.5f, y01[i].y, c.y);
        float e2 = fmaf(0.5f, y23[i].x, c.z);
        float e3 = fmaf(0.5f, y23[i].y, c.w);
        mse_acc += e0 * e0 + e1 * e1 + e2 * e2 + e3 * e3;
        float* p = &xt[w * XT_STRIDE + hc * 4];
        p[0] = c.x; p[1] = c.y; p[2] = c.z; p[3] = c.w;   // overwrite x with q
        out[OFF_INDS + (size_t)b * JV + j] = (float)kmin[i];
    }
    __syncthreads();

    // ---- coalesced crop/transpose write-out: ql[b, h, w] = xt[w][h], h < 62 ----
    for (int idx = t; idx < HH * WW; idx += 256) {
        int h = idx >> 6;
        int w = idx & 63;
        out[(size_t)b * (HH * WW) + idx] = xt[w * XT_STRIDE + h];
    }

    // ---- block reduction of mse/rate -> per-block partial (plain store) ----
#pragma unroll
    for (int off = 32; off > 0; off >>= 1) {
        mse_acc  += __shfl_down(mse_acc, off, 64);
        rate_acc += __shfl_down(rate_acc, off, 64);
    }
    int wave = t >> 6, lane = t & 63;
    if (lane == 0) { wred[wave] = mse_acc; wred[4 + wave] = rate_acc; }
    __syncthreads();
    if (t == 0) {
        ws_out[WS_MSE + b]  = wred[0] + wred[1] + wred[2] + wred[3];
        ws_out[WS_RATE + b] = wred[4] + wred[5] + wred[6] + wred[7];
    }
}

__global__ void vq_reduce(const float* __restrict__ ws, float* __restrict__ out) {
    __shared__ float wred[8];
    int t = threadIdx.x;   // 256 threads
    float m = ws[WS_MSE + t]  + ws[WS_MSE + 256 + t]  + ws[WS_MSE + 512 + t];
    float r = ws[WS_RATE + t] + ws[WS_RATE + 256 + t] + ws[WS_RATE + 512 + t];
#pragma unroll
    for (int off = 32; off > 0; off >>= 1) {
        m += __shfl_down(m, off, 64);
        r += __shfl_down(r, off, 64);
    }
    int wave = t >> 6, lane = t & 63;
    if (lane == 0) { wred[wave] = m; wred[4 + wave] = r; }
    __syncthreads();
    if (t == 0) {
        out[OFF_MSE]      = (wred[0] + wred[1] + wred[2] + wred[3]) * (1.0f / 3145728.0f);
        out[OFF_RATE]     = wred[4] + wred[5] + wred[6] + wred[7];
        out[OFF_RATE + 1] = 0.0f;
        out[OFF_RATE + 2] = 0.0f;
    }
}

extern "C" void kernel_launch(void* const* d_in, const int* in_sizes, int n_in,
                              void* d_out, int out_size, void* d_ws, size_t ws_size,
                              hipStream_t stream) {
    const float* latents  = (const float*)d_in[0];
    const float* codebook = (const float*)d_in[1];
    const float* log_pmf  = (const float*)d_in[2];
    float* out = (float*)d_out;
    float* ws  = (float*)d_ws;

    vq_main<<<BB, 256, 0, stream>>>(latents, codebook, log_pmf, ws, out);
    vq_reduce<<<1, 256, 0, stream>>>(ws, out);
}